// Round 8
// baseline (73.239 us; speedup 1.0000x reference)
//
#include <hip/hip_runtime.h>

#define BATCH  16
#define LEN    512
#define NSTATE 64
#define DMODEL 256
#define WAVES  4       // 4 adjacent d per block -> L2-merged y writes

// one DPP-add reduction level: x += dpp_move(x, ctrl); inactive lanes add 0
template<int CTRL, int RMASK>
__device__ __forceinline__ float dpp_add(float x) {
    int t = __builtin_amdgcn_update_dpp(0, __float_as_int(x), CTRL,
                                        RMASK, 0xf, true);
    return x + __int_as_float(t);
}

__global__ __launch_bounds__(WAVES * 64, 4)
void s4d_scan_kernel(const float* __restrict__ u,
                     const float* __restrict__ Lre_p, const float* __restrict__ Lim_p,
                     const float* __restrict__ Bre_p, const float* __restrict__ Bim_p,
                     const float* __restrict__ Pre_p, const float* __restrict__ Pim_p,
                     const float* __restrict__ logdt_p,
                     float* __restrict__ y)
{
    const int tid  = threadIdx.x;
    const int lane = tid & 63;
    const int widx = tid >> 6;
    const int wid  = blockIdx.x * WAVES + widx;   // 0..4095
    const int b    = wid >> 8;                    // / DMODEL
    const int d    = wid & 255;                   // % DMODEL

    // ---- per-lane (state n = lane) coefficients --------------------------
    const float dt  = expf(logdt_p[0]);
    const float Lre = Lre_p[lane];
    const float Lim = Lim_p[lane];
    const float eL  = expf(Lre);
    const float wre = -eL * cosf(Lim);            // w = -exp(Lambda)
    const float wim = -eL * sinf(Lim);
    const float mag = expf(dt * wre);             // a = exp(dt*w)
    const float are = mag * cosf(dt * wim);
    const float aim = mag * sinf(dt * wim);
    const float Bdre = dt * Bre_p[lane];
    const float Bdim = dt * Bim_p[lane];
    const float Pre  = Pre_p[lane * DMODEL + d];
    const float Pim  = Pim_p[lane * DMODEL + d];
    const float Gre = Pre * Bdre - Pim * Bdim;    // G = C*Bd (fold projection)
    const float Gim = Pre * Bdim + Pim * Bdre;

    float zre = 0.f, zim = 0.f;                   // z = C*x per state

    const float* up = u + (size_t)b * LEN * DMODEL + d;   // + t*DMODEL
    float*       yp = y + (size_t)b * LEN * DMODEL + d;

    const int tl = lane & 31;                     // output slot in store phase

    // prefetch macro-batch 0: 64 timesteps, one per lane
    float ucur = up[lane * DMODEL];

    for (int m = 0; m < LEN / 64; ++m) {
        // issue next macro-batch load now (wrap on last iter; values unused)
        const int mn = (m + 1) & (LEN / 64 - 1);
        float unext = up[(mn * 64 + lane) * DMODEL];

        #pragma unroll
        for (int half = 0; half < 2; ++half) {
            unsigned sy[32];                       // uniform (SGPR-resident)
            #pragma unroll
            for (int tau = 0; tau < 32; ++tau) {
                const float us = __uint_as_float(
                    __builtin_amdgcn_readlane(__float_as_uint(ucur),
                                              half * 32 + tau));
                // z = a*z + G*u   (6 VALU)
                const float nzre = fmaf(are, zre, fmaf(-aim, zim, Gre * us));
                const float nzim = fmaf(are, zim, fmaf( aim, zre, Gim * us));
                zre = nzre;
                zim = nzim;

                // 64-lane sum of zre on the VALU pipe (DPP tree)
                float s = zre;
                s = dpp_add<0x0B1, 0xf>(s);   // quad_perm [1,0,3,2] (xor 1)
                s = dpp_add<0x04E, 0xf>(s);   // quad_perm [2,3,0,1] (xor 2)
                s = dpp_add<0x141, 0xf>(s);   // row_half_mirror     (xor 4)
                s = dpp_add<0x140, 0xf>(s);   // row_mirror          (xor 8)
                s = dpp_add<0x142, 0xa>(s);   // row_bcast15 -> rows 1,3
                s = dpp_add<0x143, 0xc>(s);   // row_bcast31 -> rows 2,3
                // full sum now in lanes 48..63
                sy[tau] = __builtin_amdgcn_readlane(__float_as_uint(s), 63);
            }

            // pack the 32 sums into lanes 0..31 (v_writelane, const lane idx)
            unsigned vy = 0u;
#define WLANE(J) asm("v_writelane_b32 %0, %1, " #J : "+v"(vy) : "s"(sy[J]));
            WLANE(0)  WLANE(1)  WLANE(2)  WLANE(3)
            WLANE(4)  WLANE(5)  WLANE(6)  WLANE(7)
            WLANE(8)  WLANE(9)  WLANE(10) WLANE(11)
            WLANE(12) WLANE(13) WLANE(14) WLANE(15)
            WLANE(16) WLANE(17) WLANE(18) WLANE(19)
            WLANE(20) WLANE(21) WLANE(22) WLANE(23)
            WLANE(24) WLANE(25) WLANE(26) WLANE(27)
            WLANE(28) WLANE(29) WLANE(30) WLANE(31)
#undef WLANE
            if (lane < 32)
                yp[(m * 64 + half * 32 + tl) * DMODEL] = __uint_as_float(vy);
        }
        ucur = unext;
    }
}

extern "C" void kernel_launch(void* const* d_in, const int* in_sizes, int n_in,
                              void* d_out, int out_size, void* d_ws, size_t ws_size,
                              hipStream_t stream) {
    const float* u      = (const float*)d_in[0];
    const float* Lre    = (const float*)d_in[1];
    const float* Lim    = (const float*)d_in[2];
    const float* Bre    = (const float*)d_in[3];
    const float* Bim    = (const float*)d_in[4];
    const float* Pre    = (const float*)d_in[5];
    const float* Pim    = (const float*)d_in[6];
    const float* logdt  = (const float*)d_in[7];
    float* y = (float*)d_out;

    const int nblocks = (BATCH * DMODEL) / WAVES;   // 1024
    s4d_scan_kernel<<<nblocks, WAVES * 64, 0, stream>>>(
        u, Lre, Lim, Bre, Bim, Pre, Pim, logdt, y);
}